// Round 5
// baseline (473.314 us; speedup 1.0000x reference)
//
#include <hip/hip_runtime.h>

// Problem: single-head causal attention, FUSED (R7 resubmit: row-panel staging).
// B=512, T=256, C=384, H=64. Inputs fp32: x[B,T,C], Wq/Wk/Wv[C,H]. Out fp32 [B,T,H].
// Scale is C^-0.5 (note: n_embed, not head_size).
//
// R6 post-mortem: fused ~107 us; effective x-read rate ~2.2 TB/s (35% of ceiling).
// All models point at DRAM pattern: K-chunking reads 256-B segments at stride
// 1536. R7 chunks over ROWS instead: 4 panels of 64 rows; each wave stages 4
// complete rows = 6 KB fully contiguous (perfect streaming). K stays whole
// (384) per panel; waves split 4 rt x 4 ctg (3 ct). acc = 12 AGPR.
// (R4-bench was an infra failure — container acquisition — so this is an
// unmodified resubmit of R7 to preserve the A/B.)
#define B_ 512
#define T_ 256
#define C_ 384
#define H_ 64

typedef __attribute__((ext_vector_type(8))) short bf16x8;   // 4 VGPRs, MFMA A/B frag
typedef __attribute__((ext_vector_type(4))) float f32x4;    // MFMA C/D frag

// fp32 -> bf16 (RNE). Data is finite; no NaN handling needed.
__device__ __forceinline__ short f2bf(float f) {
    unsigned u = __float_as_uint(f);
    u += 0x7fffu + ((u >> 16) & 1u);
    return (short)(u >> 16);
}

// pack 4 fp32 -> 4 bf16 in one 8-B value (for ds_write_b64).
__device__ __forceinline__ unsigned long long pack4(float4 a) {
    return  (unsigned long long)(unsigned short)f2bf(a.x)
         | ((unsigned long long)(unsigned short)f2bf(a.y) << 16)
         | ((unsigned long long)(unsigned short)f2bf(a.z) << 32)
         | ((unsigned long long)(unsigned short)f2bf(a.w) << 48);
}

// ---------------------------------------------------------------------------
// Kernel 0: pack Wq|Wk|Wv (fp32, [C][H] each) into bf16 MFMA B-fragment order.
// Combined N = 192 (q:0-63, k:64-127, v:128-191). K = C = 384.
// Packed index p = ((ks*12 + ct)*64 + lane)*8 + j,
//   where n = ct*16 + (lane&15), k = ks*32 + (lane>>4)*8 + j.
// ---------------------------------------------------------------------------
__global__ void pack_w_kernel(const float* __restrict__ Wq, const float* __restrict__ Wk,
                              const float* __restrict__ Wv, short* __restrict__ wp) {
    int p = blockIdx.x * 256 + threadIdx.x;
    if (p >= 12 * 12 * 512) return;           // 73728 shorts total
    int j    = p & 7;
    int lane = (p >> 3) & 63;
    int pc   = p >> 9;                         // ks*12 + ct
    int ct = pc % 12, ks = pc / 12;
    int n  = ct * 16 + (lane & 15);
    int kk = ks * 32 + (lane >> 4) * 8 + j;
    const float* src = (n < 64) ? Wq : ((n < 128) ? Wk : Wv);
    wp[p] = f2bf(src[kk * 64 + (n & 63)]);
}

// ---------------------------------------------------------------------------
// Kernel 1 (FUSED): one block of 1024 thr (16 waves) per batch.
//
// Phase 1 (QKV GEMM, T-paneled): 4 panels of 64 rows, K whole (384).
//   - stage: wave w loads panel rows [4w,4w+4) = 6 KB CONTIGUOUS (6 dwordx4,
//     1024 B contiguous per instr), packs to bf16, ds_write_b64 into swizzled
//     X tile [64 rows][48 granules-of-16B], granule swz: low3 ^= (row&7).
//   - compute: wave w owns rt = w&3 (16 rows), cts (w>>2)*3+[0,3): per ks
//     (12): 1 A-frag ds_read_b128 from X, 3 B-frags from wp (L2), 3 MFMA.
//   - panel p+1 loads issued BEFORE panel p compute (T14 async-stage split);
//     written to X after the read-barrier.
// Epilogue per panel: acc -> Qs/Ks/Vs frag layouts (region disjoint from X).
// Phase 2: identical to R6; Pb aliases the dead X region.
//
// LDS: X 48K (|| Pb 20K in phase 2) + Qs 32K + Ks 32K + Vs 32K = 147456 B
//   -> 1 block/CU, 16 waves (4/SIMD).
// ---------------------------------------------------------------------------
__global__ __launch_bounds__(1024, 4) void fused_kernel(
    const float* __restrict__ x, const short* __restrict__ wp,
    float* __restrict__ out) {
    __shared__ char lds_raw[147456];
    char*  Xb = lds_raw;                          // phase1: 49152 B (X tile)
    short* Qs = (short*)(lds_raw + 49152);        // 32768 B
    short* Ks = (short*)(lds_raw + 81920);        // 32768 B
    short* Vs = (short*)(lds_raw + 114688);       // 32768 B
    short* Pb = (short*)lds_raw;                  // phase2: aliases X, 20480 B

    const int b = blockIdx.x;
    const int tid = threadIdx.x;
    const int w = tid >> 6, lane = tid & 63;
    const int cl = lane & 15, quad = lane >> 4;

    const float* xb = x + (long)b * (T_ * C_);
    const float4* xq = (const float4*)xb + w * 384 + lane;  // wave's linear run

    // ----- staging dest precompute (6 swizzled LDS byte addrs, p-invariant) --
    // f = w*384 + i*64 + lane indexes float4s within a panel (64 rows x 96 f4).
    // row r = f/96, col4 = f%96; granule g = col4>>1 (16B = 8 bf16), sub=col4&1.
    // dest = r*768 + ((g&~7)|((g&7)^(r&7)))*16 + sub*8.
    unsigned dst[6];
    #pragma unroll
    for (int i = 0; i < 6; i++) {
        unsigned f = (unsigned)(w * 384 + i * 64 + lane);
        unsigned r = f / 96u, c4 = f % 96u;
        unsigned g = c4 >> 1, sub = c4 & 1u;
        unsigned sw = (g & ~7u) | ((g & 7u) ^ (r & 7u));
        dst[i] = r * 768u + sw * 16u + sub * 8u;
    }

    // ----- A-frag read precompute ------------------------------------------
    // frag(ks): row = rt*16+cl, g = ks*4+quad, g' low3 ^= (cl&7).
    // addr(ks) = (rowA + e0*16 + (ks>>1)*128) ^ ((ks&1)*64)   [quad<4 => XOR ok]
    const int rt  = w & 3;
    const int ctb = (w >> 2) * 3;
    const unsigned addrA = (unsigned)((rt * 16 + cl) * 768)
                         + (((unsigned)quad ^ (unsigned)(cl & 7)) << 4);

    const short* wlB = wp + ctb * 512 + lane * 8;   // + ks*6144 + j*512

    // ----- prologue: stage panel 0 -----------------------------------------
    {
        float4 sv[6];
        #pragma unroll
        for (int i = 0; i < 6; i++) sv[i] = xq[i * 64];
        #pragma unroll
        for (int i = 0; i < 6; i++)
            *(unsigned long long*)(Xb + dst[i]) = pack4(sv[i]);
    }
    __syncthreads();

    // ----- panel loop ------------------------------------------------------
    for (int p = 0; p < 4; ++p) {
        f32x4 acc[3];
        #pragma unroll
        for (int j = 0; j < 3; j++) {
            f32x4 z = {0.f, 0.f, 0.f, 0.f};
            acc[j] = z;
        }

        // issue next panel's linear loads early (overlap with compute)
        float4 sv[6];
        if (p < 3) {
            #pragma unroll
            for (int i = 0; i < 6; i++)
                sv[i] = xq[(p + 1) * 6144 + i * 64];
        }

        // compute: 12 ks-steps over this panel
        #pragma unroll
        for (int ks = 0; ks < 12; ks++) {
            const unsigned aoff = (addrA + (unsigned)((ks >> 1) * 128))
                                ^ (unsigned)((ks & 1) * 64);
            const bf16x8 af = *(const bf16x8*)(Xb + aoff);
            const short* wk = wlB + ks * 6144;
            #pragma unroll
            for (int j = 0; j < 3; j++) {
                const bf16x8 bf = *(const bf16x8*)(wk + j * 512);
                acc[j] = __builtin_amdgcn_mfma_f32_16x16x32_bf16(af, bf, acc[j], 0, 0, 0);
            }
        }

        // epilogue: acc -> Qs/Ks/Vs. acc[j][r] is (t = ts*16 + quad*4 + r,
        // n = (ctb+j)*16 + cl), ts = p*4 + rt.
        const int ts = p * 4 + rt;
        #pragma unroll
        for (int j = 0; j < 3; j++) {
            const int ct = ctb + j;
            if (ct < 4) {           // Q: h = ct*16 + cl
                const int h = ct * 16 + cl;
                const int kk = h >> 5, hq = (h >> 3) & 3, jj = h & 7;
                #pragma unroll
                for (int r = 0; r < 4; r++)
                    Qs[(ts * 2 + kk) * 512 + ((quad * 4 + r) + 16 * hq) * 8 + jj] =
                        f2bf(acc[j][r]);
            } else if (ct < 8) {    // K: h = (ct-4)*16 + cl
                const int h = (ct - 4) * 16 + cl;
                const int kk = h >> 5, hq = (h >> 3) & 3, jj = h & 7;
                #pragma unroll
                for (int r = 0; r < 4; r++)
                    Ks[(ts * 2 + kk) * 512 + ((quad * 4 + r) + 16 * hq) * 8 + jj] =
                        f2bf(acc[j][r]);
            } else {                // V: ht = ct-8
                const int ht = ct - 8;
                #pragma unroll
                for (int r = 0; r < 4; r++) {
                    const int t = ts * 16 + quad * 4 + r;
                    Vs[((t >> 5) * 4 + ht) * 512 + (cl + 16 * ((t >> 3) & 3)) * 8 + (t & 7)] =
                        f2bf(acc[j][r]);
                }
            }
        }

        __syncthreads();            // X reads done; (p=3) also gates phase 2

        if (p < 3) {
            #pragma unroll
            for (int i = 0; i < 6; i++)
                *(unsigned long long*)(Xb + dst[i]) = pack4(sv[i]);
            __syncthreads();        // X ready for next panel
        }
    }

    // ---------------- Phase 2: causal attention ----------------------------
    // scale = 384^-0.5, with log2(e) folded in (exp via exp2).
    const float scale2 = 0.05103103630798287f * 1.4426950408889634f;

    // Row-group for this wave; SIMD-balanced bijection.
    const int rg = (w & 12) | ((w & 3) ^ (w >> 2));
    const int base = rg << 4;
    short* pb = Pb + w * 640;

    const bf16x8 qf0 = *(const bf16x8*)(Qs + (rg * 2 + 0) * 512 + lane * 8);
    const bf16x8 qf1 = *(const bf16x8*)(Qs + (rg * 2 + 1) * 512 + lane * 8);

    // S = Q K^T, tiles st <= rg (wave-uniform guards).
    f32x4 sacc[16];
    #pragma unroll
    for (int st = 0; st < 16; st++) {
        if (st > rg) continue;
        bf16x8 k0 = *(const bf16x8*)(Ks + (st * 2 + 0) * 512 + lane * 8);
        bf16x8 k1 = *(const bf16x8*)(Ks + (st * 2 + 1) * 512 + lane * 8);
        f32x4 z = {0.f, 0.f, 0.f, 0.f};
        f32x4 t = __builtin_amdgcn_mfma_f32_16x16x32_bf16(qf0, k0, z, 0, 0, 0);
        t = __builtin_amdgcn_mfma_f32_16x16x32_bf16(qf1, k1, t, 0, 0, 0);
        sacc[st] = t;
    }

    // Scale (pre-multiplied by log2e), causal mask, row max.
    float m4[4] = {-3e38f, -3e38f, -3e38f, -3e38f};
    #pragma unroll
    for (int st = 0; st < 16; st++) {
        if (st > rg) continue;
        #pragma unroll
        for (int r = 0; r < 4; r++) {
            float sv = sacc[st][r] * scale2;
            if (st * 16 + cl > base + quad * 4 + r) sv = -1e30f;
            sacc[st][r] = sv;
            m4[r] = fmaxf(m4[r], sv);
        }
    }
    #pragma unroll
    for (int d = 1; d < 16; d <<= 1)
        #pragma unroll
        for (int r = 0; r < 4; r++)
            m4[r] = fmaxf(m4[r], __shfl_xor(m4[r], d));

    // exp + row sum (masked entries -> 0 exactly).
    float l4[4] = {0.f, 0.f, 0.f, 0.f};
    #pragma unroll
    for (int st = 0; st < 16; st++) {
        if (st > rg) continue;
        #pragma unroll
        for (int r = 0; r < 4; r++) {
            float pv = exp2f(sacc[st][r] - m4[r]);
            sacc[st][r] = pv;
            l4[r] += pv;
        }
    }
    #pragma unroll
    for (int d = 1; d < 16; d <<= 1)
        #pragma unroll
        for (int r = 0; r < 4; r++)
            l4[r] += __shfl_xor(l4[r], d);

    // O = P V over s-chunks of 32 (chunks cc <= rg/2). P via Pb round-trip.
    f32x4 oacc[4];
    #pragma unroll
    for (int ht = 0; ht < 4; ht++) {
        f32x4 z = {0.f, 0.f, 0.f, 0.f};
        oacc[ht] = z;
    }
    #pragma unroll
    for (int cc = 0; cc < 8; cc++) {
        if (cc > (rg >> 1)) continue;
        #pragma unroll
        for (int half = 0; half < 2; half++) {
            const int st = cc * 2 + half;
            #pragma unroll
            for (int r = 0; r < 4; r++) {
                short pv = (st <= rg) ? f2bf(sacc[st][r]) : (short)0;
                pb[(quad * 4 + r) * 40 + half * 16 + cl] = pv;
            }
        }
        __builtin_amdgcn_wave_barrier();
        const bf16x8 pa = *(const bf16x8*)(pb + cl * 40 + quad * 8);
        #pragma unroll
        for (int ht = 0; ht < 4; ht++) {
            const bf16x8 vf = *(const bf16x8*)(Vs + (cc * 4 + ht) * 512 + lane * 8);
            oacc[ht] = __builtin_amdgcn_mfma_f32_16x16x32_bf16(pa, vf, oacc[ht], 0, 0, 0);
        }
        __builtin_amdgcn_wave_barrier();
    }

    // Out: O row r is in the same lanes as l4[r].
    #pragma unroll
    for (int r = 0; r < 4; r++) {
        const float inv = 1.0f / l4[r];
        float* op = out + (long)(b * T_ + base + quad * 4 + r) * H_ + cl;
        #pragma unroll
        for (int ht = 0; ht < 4; ht++)
            op[ht * 16] = oacc[ht][r] * inv;
    }
}

// ---------------------------------------------------------------------------
extern "C" void kernel_launch(void* const* d_in, const int* in_sizes, int n_in,
                              void* d_out, int out_size, void* d_ws, size_t ws_size,
                              hipStream_t stream) {
    const float* x  = (const float*)d_in[0];
    const float* Wq = (const float*)d_in[1];
    const float* Wk = (const float*)d_in[2];
    const float* Wv = (const float*)d_in[3];
    float* out = (float*)d_out;

    short* wp = (short*)d_ws;   // packed W: 73728 shorts = 147 KB

    pack_w_kernel<<<288, 256, 0, stream>>>(Wq, Wk, Wv, wp);
    fused_kernel<<<B_, 1024, 0, stream>>>(x, wp, out);
}